// Round 1
// baseline (68.781 us; speedup 1.0000x reference)
//
#include <hip/hip_runtime.h>
#include <hip/hip_bf16.h>
#include <stdint.h>

#define NB 4096
#define ND 512
#define TAU_ 0.02f
#define INV_TAU_ 50.0f
#define CLAMP_MAXF 1e36f

typedef __attribute__((ext_vector_type(8))) short bf16x8;
typedef __attribute__((ext_vector_type(4))) float f32x4;

// Address-space casts via integer (CK-style) to satisfy the builtin's
// AS(1)/AS(3) pointer params. Generic LDS pointer low 32 bits == LDS offset.
#define AS1(p) ((__attribute__((address_space(1))) void*)(uintptr_t)(p))
#define AS3(p) ((__attribute__((address_space(3))) void*)(uint32_t)(uintptr_t)(p))

static __device__ __forceinline__ unsigned short f2bf(float f) {
  __hip_bfloat16 h = __float2bfloat16(f);
  return *reinterpret_cast<unsigned short*>(&h);
}

// ---------------- normalize + cast to bf16 (one wave per row) ----------------
__global__ __launch_bounds__(256) void k_norm(const float* __restrict__ vis,
                                              const float* __restrict__ txt,
                                              unsigned short* __restrict__ tn_b,
                                              unsigned short* __restrict__ vn_b) {
  int wv = threadIdx.x >> 6, ln = threadIdx.x & 63;
  int r = blockIdx.x * 4 + wv;  // 0..8191: first 4096 textual, rest visual
  const float* src;
  unsigned short* dst;
  if (r < NB) {
    src = txt + (size_t)r * ND;
    dst = tn_b + (size_t)r * ND;
  } else {
    src = vis + (size_t)(r - NB) * ND;
    dst = vn_b + (size_t)(r - NB) * ND;
  }
  float4 x0 = reinterpret_cast<const float4*>(src)[ln];
  float4 x1 = reinterpret_cast<const float4*>(src)[64 + ln];
  float ss = x0.x * x0.x + x0.y * x0.y + x0.z * x0.z + x0.w * x0.w +
             x1.x * x1.x + x1.y * x1.y + x1.z * x1.z + x1.w * x1.w;
#pragma unroll
  for (int o = 32; o; o >>= 1) ss += __shfl_xor(ss, o, 64);
  float inv = 1.0f / fmaxf(sqrtf(ss), 1e-12f);
  ushort4 p0, p1;
  p0.x = f2bf(x0.x * inv); p0.y = f2bf(x0.y * inv);
  p0.z = f2bf(x0.z * inv); p0.w = f2bf(x0.w * inv);
  p1.x = f2bf(x1.x * inv); p1.y = f2bf(x1.y * inv);
  p1.z = f2bf(x1.z * inv); p1.w = f2bf(x1.w * inv);
  reinterpret_cast<ushort4*>(dst)[ln] = p0;
  reinterpret_cast<ushort4*>(dst)[64 + ln] = p1;
}

// ---------------- n_neg0 = sum(pid != pid[0]) ----------------
__global__ __launch_bounds__(256) void k_nneg(const int* __restrict__ pid,
                                              float* __restrict__ nneg) {
  __shared__ float r4[4];
  int tid = threadIdx.x;
  int pid0 = pid[0];
  float c = 0.f;
  for (int j = tid; j < NB; j += 256) c += (pid[j] != pid0) ? 1.0f : 0.0f;
#pragma unroll
  for (int o = 32; o; o >>= 1) c += __shfl_xor(c, o, 64);
  if ((tid & 63) == 0) r4[tid >> 6] = c;
  __syncthreads();
  if (tid == 0) nneg[0] = r4[0] + r4[1] + r4[2] + r4[3];
}

// ---------------- scores = tn @ vn^T  (bf16 MFMA, 128x128 tile, BK=32) -------
__global__ __launch_bounds__(256) void k_gemm(const unsigned short* __restrict__ A,
                                              const unsigned short* __restrict__ Bm,
                                              float* __restrict__ C) {
  __shared__ unsigned short sA[128 * 32];
  __shared__ unsigned short sB[128 * 32];
  int tid = threadIdx.x;
  int wv = tid >> 6, ln = tid & 63;
  int bm = blockIdx.x >> 5;  // 32 column-blocks
  int bn = blockIdx.x & 31;
  int wr = wv >> 1, wc = wv & 1;
  f32x4 acc[4][4] = {};
  int frow = ln & 15, fkg = ln >> 4;
  const unsigned short* Abase = A + (size_t)(bm * 128) * ND;
  const unsigned short* Bbase = Bm + (size_t)(bn * 128) * ND;

  for (int k0 = 0; k0 < ND; k0 += 32) {
#pragma unroll
    for (int q = 0; q < 2; ++q) {
      int t = q * 256 + tid;
      int rr = t >> 2;          // tile row 0..127
      int cc = (t & 3) << 3;    // k offset within tile (0,8,16,24)
      __builtin_amdgcn_global_load_lds(AS1(Abase + (size_t)rr * ND + k0 + cc),
                                       AS3((char*)sA + (q * 256 + wv * 64) * 16),
                                       16, 0, 0);
      __builtin_amdgcn_global_load_lds(AS1(Bbase + (size_t)rr * ND + k0 + cc),
                                       AS3((char*)sB + (q * 256 + wv * 64) * 16),
                                       16, 0, 0);
    }
    __syncthreads();  // drains vmcnt; tiles ready

    bf16x8 af[4], bfr[4];
#pragma unroll
    for (int mi = 0; mi < 4; ++mi)
      af[mi] = *reinterpret_cast<const bf16x8*>(
          (const char*)sA + (wr * 64 + mi * 16 + frow) * 64 + fkg * 16);
#pragma unroll
    for (int ni = 0; ni < 4; ++ni)
      bfr[ni] = *reinterpret_cast<const bf16x8*>(
          (const char*)sB + (wc * 64 + ni * 16 + frow) * 64 + fkg * 16);
#pragma unroll
    for (int mi = 0; mi < 4; ++mi)
#pragma unroll
      for (int ni = 0; ni < 4; ++ni)
        acc[mi][ni] =
            __builtin_amdgcn_mfma_f32_16x16x32_bf16(af[mi], bfr[ni], acc[mi][ni], 0, 0, 0);
    __syncthreads();  // all reads done before next stage overwrites
  }

  // C/D layout: col = lane&15, row = (lane>>4)*4 + reg
  float* Cp = C + (size_t)(bm * 128 + wr * 64 + (ln >> 4) * 4) * NB +
              bn * 128 + wc * 64 + (ln & 15);
#pragma unroll
  for (int mi = 0; mi < 4; ++mi)
#pragma unroll
    for (int v = 0; v < 4; ++v) {
      float* rp = Cp + (size_t)(mi * 16 + v) * NB;
#pragma unroll
      for (int ni = 0; ni < 4; ++ni) rp[ni * 16] = acc[mi][ni][v];
    }
}

// ---------------- per-row masked exp reductions + losses ----------------
__global__ __launch_bounds__(256) void k_row(const float* __restrict__ scores,
                                             const int* __restrict__ pid,
                                             const float* __restrict__ margins,
                                             const float* __restrict__ unc,
                                             const int* __restrict__ stypes,
                                             const float* __restrict__ nneg,
                                             float* __restrict__ psl,
                                             float* __restrict__ uw) {
  __shared__ float red[3][4];
  int tid = threadIdx.x;
  int i = blockIdx.x;
  const float* row = scores + (size_t)i * NB;
  int pid0 = pid[0];
  float sp = 0.f, sn = 0.f, sa = 0.f, s0v = 0.f;
#pragma unroll
  for (int q = 0; q < 16; ++q) {
    int j = q * 256 + tid;
    float s = row[j];          // scalar dword loads: scores base is only 4B-aligned
    float e = expf(s * INV_TAU_);
    if (pid[j] == pid0) {
      sp += e;
      sa += e * s;
    } else {
      sn += e;
    }
    if (q == 0 && tid == 0) s0v = s;
  }
#pragma unroll
  for (int o = 32; o; o >>= 1) {
    sp += __shfl_xor(sp, o, 64);
    sn += __shfl_xor(sn, o, 64);
    sa += __shfl_xor(sa, o, 64);
  }
  if ((tid & 63) == 0) {
    red[0][tid >> 6] = sp;
    red[1][tid >> 6] = sn;
    red[2][tid >> 6] = sa;
  }
  __syncthreads();
  if (tid == 0) {
    sp = red[0][0] + red[0][1] + red[0][2] + red[0][3];
    sn = red[1][0] + red[1][1] + red[1][2] + red[1][3];
    sa = red[2][0] + red[2][1] + red[2][2] + red[2][3];
    float m = margins[i];
    float li2t = fmaxf(-(sa / sp) + TAU_ * logf(fminf(sn, CLAMP_MAXF)) + m, 0.f);
    float t2i = fminf(expf(s0v * INV_TAU_) * nneg[0], CLAMP_MAXF);
    float lt2i = fmaxf(-s0v + TAU_ * logf(t2i) + m, 0.f);
    psl[i] = li2t + lt2i;
    float w = 1.f;
    if (stypes[i] == 2) w = fminf(fmaxf(1.f - 0.5f * unc[i], 0.1f), 1.f);
    uw[i] = w;
  }
}

// ---------------- final weighted mean ----------------
__global__ __launch_bounds__(256) void k_final(const float* __restrict__ psl,
                                               const float* __restrict__ uw,
                                               float* __restrict__ out) {
  __shared__ float rn[4], rd[4];
  int tid = threadIdx.x;
  float num = 0.f, den = 0.f;
  for (int j = tid; j < NB; j += 256) {
    float w = uw[j];
    num += psl[j] * w;
    den += w;
  }
#pragma unroll
  for (int o = 32; o; o >>= 1) {
    num += __shfl_xor(num, o, 64);
    den += __shfl_xor(den, o, 64);
  }
  if ((tid & 63) == 0) {
    rn[tid >> 6] = num;
    rd[tid >> 6] = den;
  }
  __syncthreads();
  if (tid == 0) {
    num = rn[0] + rn[1] + rn[2] + rn[3];
    den = rd[0] + rd[1] + rd[2] + rd[3];
    out[0] = num / den;
  }
}

extern "C" void kernel_launch(void* const* d_in, const int* in_sizes, int n_in,
                              void* d_out, int out_size, void* d_ws, size_t ws_size,
                              hipStream_t stream) {
  const float* vis = (const float*)d_in[0];
  const float* txt = (const float*)d_in[1];
  const int* pid = (const int*)d_in[2];
  const float* margins = (const float*)d_in[3];
  const float* unc = (const float*)d_in[4];
  const int* stypes = (const int*)d_in[5];

  float* out = (float*)d_out;
  float* out_psl = out + 1;
  float* out_uw = out + 1 + NB;
  float* out_scores = out + 1 + 2 * NB;  // 4B-aligned only!

  unsigned short* tn_b = (unsigned short*)d_ws;            // textual, normalized bf16
  unsigned short* vn_b = tn_b + (size_t)NB * ND;           // visual, normalized bf16
  float* nneg = (float*)(vn_b + (size_t)NB * ND);

  k_norm<<<2048, 256, 0, stream>>>(vis, txt, tn_b, vn_b);
  k_nneg<<<1, 256, 0, stream>>>(pid, nneg);
  k_gemm<<<1024, 256, 0, stream>>>(tn_b, vn_b, out_scores);
  k_row<<<NB, 256, 0, stream>>>(out_scores, pid, margins, unc, stypes, nneg,
                                out_psl, out_uw);
  k_final<<<1, 256, 0, stream>>>(out_psl, out_uw, out);
}

// Round 2
// 63.813 us; speedup vs baseline: 1.0779x; 1.0779x over previous
//
#include <hip/hip_runtime.h>
#include <hip/hip_bf16.h>
#include <stdint.h>

#define NB 4096
#define ND 512
#define TAU_ 0.02f
#define INV_TAU_ 50.0f
#define CLAMP_MAXF 1e36f

typedef __attribute__((ext_vector_type(8))) short bf16x8;
typedef __attribute__((ext_vector_type(4))) float f32x4;

#define AS1(p) ((__attribute__((address_space(1))) void*)(uintptr_t)(p))
#define AS3(p) ((__attribute__((address_space(3))) void*)(uint32_t)(uintptr_t)(p))

static __device__ __forceinline__ unsigned short f2bf(float f) {
  __hip_bfloat16 h = __float2bfloat16(f);
  return *reinterpret_cast<unsigned short*>(&h);
}

// ---------------- normalize + cast to bf16 (one wave per row) ----------------
__global__ __launch_bounds__(256) void k_norm(const float* __restrict__ vis,
                                              const float* __restrict__ txt,
                                              unsigned short* __restrict__ tn_b,
                                              unsigned short* __restrict__ vn_b) {
  int wv = threadIdx.x >> 6, ln = threadIdx.x & 63;
  int r = blockIdx.x * 4 + wv;
  const float* src;
  unsigned short* dst;
  if (r < NB) {
    src = txt + (size_t)r * ND;
    dst = tn_b + (size_t)r * ND;
  } else {
    src = vis + (size_t)(r - NB) * ND;
    dst = vn_b + (size_t)(r - NB) * ND;
  }
  float4 x0 = reinterpret_cast<const float4*>(src)[ln];
  float4 x1 = reinterpret_cast<const float4*>(src)[64 + ln];
  float ss = x0.x * x0.x + x0.y * x0.y + x0.z * x0.z + x0.w * x0.w +
             x1.x * x1.x + x1.y * x1.y + x1.z * x1.z + x1.w * x1.w;
#pragma unroll
  for (int o = 32; o; o >>= 1) ss += __shfl_xor(ss, o, 64);
  float inv = 1.0f / fmaxf(sqrtf(ss), 1e-12f);
  ushort4 p0, p1;
  p0.x = f2bf(x0.x * inv); p0.y = f2bf(x0.y * inv);
  p0.z = f2bf(x0.z * inv); p0.w = f2bf(x0.w * inv);
  p1.x = f2bf(x1.x * inv); p1.y = f2bf(x1.y * inv);
  p1.z = f2bf(x1.z * inv); p1.w = f2bf(x1.w * inv);
  reinterpret_cast<ushort4*>(dst)[ln] = p0;
  reinterpret_cast<ushort4*>(dst)[64 + ln] = p1;
}

// ---------------- n_neg0 = sum(pid != pid[0]) ----------------
__global__ __launch_bounds__(256) void k_nneg(const int* __restrict__ pid,
                                              float* __restrict__ nneg) {
  __shared__ float r4[4];
  int tid = threadIdx.x;
  int pid0 = pid[0];
  float c = 0.f;
  for (int j = tid; j < NB; j += 256) c += (pid[j] != pid0) ? 1.0f : 0.0f;
#pragma unroll
  for (int o = 32; o; o >>= 1) c += __shfl_xor(c, o, 64);
  if ((tid & 63) == 0) r4[tid >> 6] = c;
  __syncthreads();
  if (tid == 0) nneg[0] = r4[0] + r4[1] + r4[2] + r4[3];
}

// ------- scores = tn @ vn^T (bf16 MFMA, 128x128, BK=64, XOR-swizzled LDS) ----
// Fused epilogue: per-row masked exp partial sums -> partials[4096][32][3]
__global__ __launch_bounds__(256) void k_gemm(const unsigned short* __restrict__ A,
                                              const unsigned short* __restrict__ Bm,
                                              const int* __restrict__ pid,
                                              float* __restrict__ C,
                                              float* __restrict__ partials) {
  __shared__ unsigned short sA[128 * 64];
  __shared__ unsigned short sB[128 * 64];
  int tid = threadIdx.x;
  int wv = tid >> 6, ln = tid & 63;
  int bm = blockIdx.x >> 5;
  int bn = blockIdx.x & 31;
  int wr = wv >> 1, wc = wv & 1;
  f32x4 acc[4][4] = {};
  int frow = ln & 15, fkg = ln >> 4;
  const unsigned short* Abase = A + (size_t)(bm * 128) * ND;
  const unsigned short* Bbase = Bm + (size_t)(bn * 128) * ND;

  for (int k0 = 0; k0 < ND; k0 += 64) {
    // Stage 128x64 tiles. LDS dest linear (thread T -> byte T*16, row=T>>3,
    // slot'=T&7); global source pre-swizzled: slot = slot' ^ (row&7).
#pragma unroll
    for (int p = 0; p < 4; ++p) {
      int T = p * 256 + tid;
      int rr = T >> 3;
      int slot = (T & 7) ^ (rr & 7);
      __builtin_amdgcn_global_load_lds(AS1(Abase + (size_t)rr * ND + k0 + slot * 8),
                                       AS3((char*)sA + (p * 256 + wv * 64) * 16),
                                       16, 0, 0);
      __builtin_amdgcn_global_load_lds(AS1(Bbase + (size_t)rr * ND + k0 + slot * 8),
                                       AS3((char*)sB + (p * 256 + wv * 64) * 16),
                                       16, 0, 0);
    }
    __syncthreads();

#pragma unroll
    for (int ksub = 0; ksub < 2; ++ksub) {
      bf16x8 af[4], bfr[4];
#pragma unroll
      for (int mi = 0; mi < 4; ++mi) {
        int row = wr * 64 + mi * 16 + frow;
        af[mi] = *reinterpret_cast<const bf16x8*>(
            (const char*)sA + row * 128 + (((ksub * 4 + fkg) ^ (row & 7)) * 16));
      }
#pragma unroll
      for (int ni = 0; ni < 4; ++ni) {
        int row = wc * 64 + ni * 16 + frow;
        bfr[ni] = *reinterpret_cast<const bf16x8*>(
            (const char*)sB + row * 128 + (((ksub * 4 + fkg) ^ (row & 7)) * 16));
      }
#pragma unroll
      for (int mi = 0; mi < 4; ++mi)
#pragma unroll
        for (int ni = 0; ni < 4; ++ni)
          acc[mi][ni] = __builtin_amdgcn_mfma_f32_16x16x32_bf16(af[mi], bfr[ni],
                                                                acc[mi][ni], 0, 0, 0);
    }
    __syncthreads();
  }

  // Epilogue: C store + fused masked exp row-partials.
  int pid0 = pid[0];
  int eq[4];
#pragma unroll
  for (int ni = 0; ni < 4; ++ni)
    eq[ni] = (pid[bn * 128 + wc * 64 + ni * 16 + frow] == pid0) ? 1 : 0;

  float* pb = reinterpret_cast<float*>(sA);  // [2 wc][128 rows][3], reuses sA
  float* Cp = C + (size_t)(bm * 128 + wr * 64 + fkg * 4) * NB + bn * 128 +
              wc * 64 + frow;
#pragma unroll
  for (int mi = 0; mi < 4; ++mi) {
#pragma unroll
    for (int v = 0; v < 4; ++v) {
      float sp = 0.f, sn = 0.f, sa = 0.f;
      float* rp = Cp + (size_t)(mi * 16 + v) * NB;
#pragma unroll
      for (int ni = 0; ni < 4; ++ni) {
        float s = acc[mi][ni][v];
        rp[ni * 16] = s;
        float e = __expf(s * INV_TAU_);
        if (eq[ni]) {
          sp += e;
          sa += e * s;
        } else {
          sn += e;
        }
      }
#pragma unroll
      for (int o = 1; o < 16; o <<= 1) {
        sp += __shfl_xor(sp, o, 64);
        sn += __shfl_xor(sn, o, 64);
        sa += __shfl_xor(sa, o, 64);
      }
      if (frow == 0) {
        int row = wr * 64 + mi * 16 + fkg * 4 + v;
        pb[(wc * 128 + row) * 3 + 0] = sp;
        pb[(wc * 128 + row) * 3 + 1] = sn;
        pb[(wc * 128 + row) * 3 + 2] = sa;
      }
    }
  }
  __syncthreads();
  if (tid < 128) {
    float sp = pb[tid * 3 + 0] + pb[(128 + tid) * 3 + 0];
    float sn = pb[tid * 3 + 1] + pb[(128 + tid) * 3 + 1];
    float sa = pb[tid * 3 + 2] + pb[(128 + tid) * 3 + 2];
    float* pout = partials + ((size_t)(bm * 128 + tid) * 32 + bn) * 3;
    pout[0] = sp;
    pout[1] = sn;
    pout[2] = sa;
  }
}

// ---------------- combine partials -> per-sample losses ----------------
__global__ __launch_bounds__(256) void k_row2(const float* __restrict__ partials,
                                              const float* __restrict__ scores,
                                              const float* __restrict__ margins,
                                              const float* __restrict__ unc,
                                              const int* __restrict__ stypes,
                                              const float* __restrict__ nneg,
                                              float* __restrict__ psl,
                                              float* __restrict__ uw) {
  int wv = threadIdx.x >> 6, ln = threadIdx.x & 63;
  int row = blockIdx.x * 4 + wv;
  const float* p = partials + (size_t)row * 32 * 3;
  float sp = 0.f, sn = 0.f, sa = 0.f;
  if (ln < 32) {
    sp = p[ln * 3 + 0];
    sn = p[ln * 3 + 1];
    sa = p[ln * 3 + 2];
  }
#pragma unroll
  for (int o = 1; o < 32; o <<= 1) {
    sp += __shfl_xor(sp, o, 64);
    sn += __shfl_xor(sn, o, 64);
    sa += __shfl_xor(sa, o, 64);
  }
  if (ln == 0) {
    float s0v = scores[(size_t)row * NB];
    float m = margins[row];
    float li2t = fmaxf(-(sa / sp) + TAU_ * logf(fminf(sn, CLAMP_MAXF)) + m, 0.f);
    float t2i = fminf(__expf(s0v * INV_TAU_) * nneg[0], CLAMP_MAXF);
    float lt2i = fmaxf(-s0v + TAU_ * logf(t2i) + m, 0.f);
    psl[row] = li2t + lt2i;
    float w = 1.f;
    if (stypes[row] == 2) w = fminf(fmaxf(1.f - 0.5f * unc[row], 0.1f), 1.f);
    uw[row] = w;
  }
}

// ---------------- final weighted mean ----------------
__global__ __launch_bounds__(256) void k_final(const float* __restrict__ psl,
                                               const float* __restrict__ uw,
                                               float* __restrict__ out) {
  __shared__ float rn[4], rd[4];
  int tid = threadIdx.x;
  float num = 0.f, den = 0.f;
  for (int j = tid; j < NB; j += 256) {
    float w = uw[j];
    num += psl[j] * w;
    den += w;
  }
#pragma unroll
  for (int o = 32; o; o >>= 1) {
    num += __shfl_xor(num, o, 64);
    den += __shfl_xor(den, o, 64);
  }
  if ((tid & 63) == 0) {
    rn[tid >> 6] = num;
    rd[tid >> 6] = den;
  }
  __syncthreads();
  if (tid == 0) {
    num = rn[0] + rn[1] + rn[2] + rn[3];
    den = rd[0] + rd[1] + rd[2] + rd[3];
    out[0] = num / den;
  }
}

extern "C" void kernel_launch(void* const* d_in, const int* in_sizes, int n_in,
                              void* d_out, int out_size, void* d_ws, size_t ws_size,
                              hipStream_t stream) {
  const float* vis = (const float*)d_in[0];
  const float* txt = (const float*)d_in[1];
  const int* pid = (const int*)d_in[2];
  const float* margins = (const float*)d_in[3];
  const float* unc = (const float*)d_in[4];
  const int* stypes = (const int*)d_in[5];

  float* out = (float*)d_out;
  float* out_psl = out + 1;
  float* out_uw = out + 1 + NB;
  float* out_scores = out + 1 + 2 * NB;  // 4B-aligned only

  unsigned short* tn_b = (unsigned short*)d_ws;
  unsigned short* vn_b = tn_b + (size_t)NB * ND;
  float* nneg = (float*)(vn_b + (size_t)NB * ND);
  float* partials = nneg + 4;  // [4096][32][3]

  k_norm<<<2048, 256, 0, stream>>>(vis, txt, tn_b, vn_b);
  k_nneg<<<1, 256, 0, stream>>>(pid, nneg);
  k_gemm<<<1024, 256, 0, stream>>>(tn_b, vn_b, pid, out_scores, partials);
  k_row2<<<NB / 4, 256, 0, stream>>>(partials, out_scores, margins, unc, stypes,
                                     nneg, out_psl, out_uw);
  k_final<<<1, 256, 0, stream>>>(out_psl, out_uw, out);
}

// Round 3
// 51.013 us; speedup vs baseline: 1.3483x; 1.2509x over previous
//
#include <hip/hip_runtime.h>
#include <hip/hip_bf16.h>
#include <stdint.h>

#define NB 4096
#define ND 512
#define TAU_ 0.02f
#define INV_TAU_ 50.0f
#define CLAMP_MAXF 1e36f

typedef __attribute__((ext_vector_type(8))) short bf16x8;
typedef __attribute__((ext_vector_type(4))) float f32x4;

#define AS1(p) ((__attribute__((address_space(1))) void*)(uintptr_t)(p))
#define AS3(p) ((__attribute__((address_space(3))) void*)(uint32_t)(uintptr_t)(p))

static __device__ __forceinline__ unsigned short f2bf(float f) {
  __hip_bfloat16 h = __float2bfloat16(f);
  return *reinterpret_cast<unsigned short*>(&h);
}

// -------- normalize + cast to bf16 (one wave per row); last block: n_neg0 ----
__global__ __launch_bounds__(256) void k_norm(const float* __restrict__ vis,
                                              const float* __restrict__ txt,
                                              const int* __restrict__ pid,
                                              unsigned short* __restrict__ tn_b,
                                              unsigned short* __restrict__ vn_b,
                                              float* __restrict__ nneg) {
  if (blockIdx.x == 2048) {  // fused n_neg0 = sum(pid != pid[0])
    __shared__ float r4[4];
    int tid = threadIdx.x;
    int pid0 = pid[0];
    float c = 0.f;
    for (int j = tid; j < NB; j += 256) c += (pid[j] != pid0) ? 1.0f : 0.0f;
#pragma unroll
    for (int o = 32; o; o >>= 1) c += __shfl_xor(c, o, 64);
    if ((tid & 63) == 0) r4[tid >> 6] = c;
    __syncthreads();
    if (tid == 0) nneg[0] = r4[0] + r4[1] + r4[2] + r4[3];
    return;
  }
  int wv = threadIdx.x >> 6, ln = threadIdx.x & 63;
  int r = blockIdx.x * 4 + wv;
  const float* src;
  unsigned short* dst;
  if (r < NB) {
    src = txt + (size_t)r * ND;
    dst = tn_b + (size_t)r * ND;
  } else {
    src = vis + (size_t)(r - NB) * ND;
    dst = vn_b + (size_t)(r - NB) * ND;
  }
  float4 x0 = reinterpret_cast<const float4*>(src)[ln];
  float4 x1 = reinterpret_cast<const float4*>(src)[64 + ln];
  float ss = x0.x * x0.x + x0.y * x0.y + x0.z * x0.z + x0.w * x0.w +
             x1.x * x1.x + x1.y * x1.y + x1.z * x1.z + x1.w * x1.w;
#pragma unroll
  for (int o = 32; o; o >>= 1) ss += __shfl_xor(ss, o, 64);
  float inv = 1.0f / fmaxf(sqrtf(ss), 1e-12f);
  ushort4 p0, p1;
  p0.x = f2bf(x0.x * inv); p0.y = f2bf(x0.y * inv);
  p0.z = f2bf(x0.z * inv); p0.w = f2bf(x0.w * inv);
  p1.x = f2bf(x1.x * inv); p1.y = f2bf(x1.y * inv);
  p1.z = f2bf(x1.z * inv); p1.w = f2bf(x1.w * inv);
  reinterpret_cast<ushort4*>(dst)[ln] = p0;
  reinterpret_cast<ushort4*>(dst)[64 + ln] = p1;
}

// --- scores = tn @ vn^T: 256x256 tile, BK=64, 8 waves, 2-phase dbuf LDS ------
// stage(t+1) issued BEFORE compute(t); single barrier per K-step (its
// vmcnt(0) drain lands after the MFMA phase -> load latency hidden).
// Fused epilogue: masked exp row-partials -> partials[4096][16][3].
__global__ __launch_bounds__(512, 2) void k_gemm(const unsigned short* __restrict__ A,
                                                 const unsigned short* __restrict__ Bm,
                                                 const int* __restrict__ pid,
                                                 float* __restrict__ C,
                                                 float* __restrict__ partials) {
  __shared__ unsigned short smem[2][2][256 * 64];  // [buf][A/B][row*64+k] 128KB
  int tid = threadIdx.x;
  int wv = tid >> 6, ln = tid & 63;
  int bm = blockIdx.x >> 4;
  int bn = blockIdx.x & 15;
  int wr = wv >> 2, wc = wv & 3;  // wave tile: rows wr*128+[0,128), cols wc*64+[0,64)
  int frow = ln & 15, fkg = ln >> 4;
  f32x4 acc[8][4] = {};
  const unsigned short* Abase = A + (size_t)(bm * 256) * ND;
  const unsigned short* Bbase = Bm + (size_t)(bn * 256) * ND;

#define STAGE(buf, k0)                                                          \
  {                                                                             \
    _Pragma("unroll") for (int p = 0; p < 4; ++p) {                             \
      int s = p * 512 + tid;                                                    \
      int rr = s >> 3;                                                          \
      int slot = (s & 7) ^ (rr & 7); /* pre-swizzled global source */           \
      __builtin_amdgcn_global_load_lds(                                         \
          AS1(Abase + (size_t)rr * ND + (k0) + slot * 8),                       \
          AS3((char*)&smem[buf][0][0] + (p * 512 + wv * 64) * 16), 16, 0, 0);   \
      __builtin_amdgcn_global_load_lds(                                         \
          AS1(Bbase + (size_t)rr * ND + (k0) + slot * 8),                       \
          AS3((char*)&smem[buf][1][0] + (p * 512 + wv * 64) * 16), 16, 0, 0);   \
    }                                                                           \
  }

  STAGE(0, 0);
  __syncthreads();
  int buf = 0;
  for (int t = 0; t < 8; ++t) {
    if (t < 7) STAGE(buf ^ 1, (t + 1) * 64);  // prefetch next K-tile
    const char* pA = (const char*)&smem[buf][0][0];
    const char* pB = (const char*)&smem[buf][1][0];
#pragma unroll
    for (int ksub = 0; ksub < 2; ++ksub) {
      bf16x8 af[8], bfr[4];
#pragma unroll
      for (int mi = 0; mi < 8; ++mi) {
        int row = wr * 128 + mi * 16 + frow;
        af[mi] = *reinterpret_cast<const bf16x8*>(
            pA + row * 128 + (((ksub * 4 + fkg) ^ (row & 7)) * 16));
      }
#pragma unroll
      for (int ni = 0; ni < 4; ++ni) {
        int row = wc * 64 + ni * 16 + frow;
        bfr[ni] = *reinterpret_cast<const bf16x8*>(
            pB + row * 128 + (((ksub * 4 + fkg) ^ (row & 7)) * 16));
      }
#pragma unroll
      for (int mi = 0; mi < 8; ++mi)
#pragma unroll
        for (int ni = 0; ni < 4; ++ni)
          acc[mi][ni] = __builtin_amdgcn_mfma_f32_16x16x32_bf16(af[mi], bfr[ni],
                                                                acc[mi][ni], 0, 0, 0);
    }
    __syncthreads();  // drains vmcnt(0)+lgkmcnt(0): prefetched tile ready,
    buf ^= 1;         // all reads of old buf done
  }

  // Epilogue: C store + fused masked exp row-partials.
  int pid0 = pid[0];
  int eq[4];
#pragma unroll
  for (int ni = 0; ni < 4; ++ni)
    eq[ni] = (pid[bn * 256 + wc * 64 + ni * 16 + frow] == pid0) ? 1 : 0;

  float* pb = reinterpret_cast<float*>(&smem[0][0][0]);  // [4 wc][256 rows][3]
  float* Cp = C + (size_t)(bm * 256 + wr * 128 + fkg * 4) * NB + bn * 256 +
              wc * 64 + frow;
#pragma unroll
  for (int mi = 0; mi < 8; ++mi) {
#pragma unroll
    for (int v = 0; v < 4; ++v) {
      float sp = 0.f, sn = 0.f, sa = 0.f;
      float* rp = Cp + (size_t)(mi * 16 + v) * NB;
#pragma unroll
      for (int ni = 0; ni < 4; ++ni) {
        float s = acc[mi][ni][v];
        rp[ni * 16] = s;
        float e = __expf(s * INV_TAU_);
        if (eq[ni]) {
          sp += e;
          sa += e * s;
        } else {
          sn += e;
        }
      }
#pragma unroll
      for (int o = 1; o < 16; o <<= 1) {
        sp += __shfl_xor(sp, o, 64);
        sn += __shfl_xor(sn, o, 64);
        sa += __shfl_xor(sa, o, 64);
      }
      if (frow == 0) {
        int row = wr * 128 + mi * 16 + fkg * 4 + v;
        pb[(wc * 256 + row) * 3 + 0] = sp;
        pb[(wc * 256 + row) * 3 + 1] = sn;
        pb[(wc * 256 + row) * 3 + 2] = sa;
      }
    }
  }
  __syncthreads();
  if (tid < 256) {
    float sp = 0.f, sn = 0.f, sa = 0.f;
#pragma unroll
    for (int w = 0; w < 4; ++w) {
      sp += pb[(w * 256 + tid) * 3 + 0];
      sn += pb[(w * 256 + tid) * 3 + 1];
      sa += pb[(w * 256 + tid) * 3 + 2];
    }
    float* pout = partials + ((size_t)(bm * 256 + tid) * 16 + bn) * 3;
    pout[0] = sp;
    pout[1] = sn;
    pout[2] = sa;
  }
}

// ---------------- combine partials -> per-sample losses ----------------
__global__ __launch_bounds__(256) void k_row2(const float* __restrict__ partials,
                                              const float* __restrict__ scores,
                                              const float* __restrict__ margins,
                                              const float* __restrict__ unc,
                                              const int* __restrict__ stypes,
                                              const float* __restrict__ nneg,
                                              float* __restrict__ psl,
                                              float* __restrict__ uw) {
  int wv = threadIdx.x >> 6, ln = threadIdx.x & 63;
  int row = blockIdx.x * 4 + wv;
  const float* p = partials + (size_t)row * 16 * 3;
  float sp = 0.f, sn = 0.f, sa = 0.f;
  if (ln < 16) {
    sp = p[ln * 3 + 0];
    sn = p[ln * 3 + 1];
    sa = p[ln * 3 + 2];
  }
#pragma unroll
  for (int o = 1; o < 16; o <<= 1) {
    sp += __shfl_xor(sp, o, 64);
    sn += __shfl_xor(sn, o, 64);
    sa += __shfl_xor(sa, o, 64);
  }
  if (ln == 0) {
    float s0v = scores[(size_t)row * NB];
    float m = margins[row];
    float li2t = fmaxf(-(sa / sp) + TAU_ * logf(fminf(sn, CLAMP_MAXF)) + m, 0.f);
    float t2i = fminf(__expf(s0v * INV_TAU_) * nneg[0], CLAMP_MAXF);
    float lt2i = fmaxf(-s0v + TAU_ * logf(t2i) + m, 0.f);
    psl[row] = li2t + lt2i;
    float w = 1.f;
    if (stypes[row] == 2) w = fminf(fmaxf(1.f - 0.5f * unc[row], 0.1f), 1.f);
    uw[row] = w;
  }
}

// ---------------- final weighted mean ----------------
__global__ __launch_bounds__(256) void k_final(const float* __restrict__ psl,
                                               const float* __restrict__ uw,
                                               float* __restrict__ out) {
  __shared__ float rn[4], rd[4];
  int tid = threadIdx.x;
  float num = 0.f, den = 0.f;
  for (int j = tid; j < NB; j += 256) {
    float w = uw[j];
    num += psl[j] * w;
    den += w;
  }
#pragma unroll
  for (int o = 32; o; o >>= 1) {
    num += __shfl_xor(num, o, 64);
    den += __shfl_xor(den, o, 64);
  }
  if ((tid & 63) == 0) {
    rn[tid >> 6] = num;
    rd[tid >> 6] = den;
  }
  __syncthreads();
  if (tid == 0) {
    num = rn[0] + rn[1] + rn[2] + rn[3];
    den = rd[0] + rd[1] + rd[2] + rd[3];
    out[0] = num / den;
  }
}

extern "C" void kernel_launch(void* const* d_in, const int* in_sizes, int n_in,
                              void* d_out, int out_size, void* d_ws, size_t ws_size,
                              hipStream_t stream) {
  const float* vis = (const float*)d_in[0];
  const float* txt = (const float*)d_in[1];
  const int* pid = (const int*)d_in[2];
  const float* margins = (const float*)d_in[3];
  const float* unc = (const float*)d_in[4];
  const int* stypes = (const int*)d_in[5];

  float* out = (float*)d_out;
  float* out_psl = out + 1;
  float* out_uw = out + 1 + NB;
  float* out_scores = out + 1 + 2 * NB;  // 4B-aligned only

  unsigned short* tn_b = (unsigned short*)d_ws;
  unsigned short* vn_b = tn_b + (size_t)NB * ND;
  float* nneg = (float*)(vn_b + (size_t)NB * ND);
  float* partials = nneg + 4;  // [4096][16][3]

  k_norm<<<2049, 256, 0, stream>>>(vis, txt, pid, tn_b, vn_b, nneg);
  k_gemm<<<256, 512, 0, stream>>>(tn_b, vn_b, pid, out_scores, partials);
  k_row2<<<NB / 4, 256, 0, stream>>>(partials, out_scores, margins, unc, stypes,
                                     nneg, out_psl, out_uw);
  k_final<<<1, 256, 0, stream>>>(out_psl, out_uw, out);
}